// Round 4
// baseline (3261.081 us; speedup 1.0000x reference)
//
#include <hip/hip_runtime.h>
#include <math.h>

// PointNet++ SetAbstraction for MI355X.
// B=4 N=8192 M=2048 K=64 C_IN=64, dims 67->64->64->128, radius 0.2.
// Exactness-critical paths (FPS argmax, ball-query radius test) use
// __f*_rn intrinsics to bit-match plain IEEE mul/add (no FMA contraction).

constexpr int B = 4, N = 8192, M = 2048, K = 64;
constexpr int C0 = 67;              // 3 + 64 input channels
constexpr int NB_CHAIN = B * M;     // one block per (b,m) = 8192
constexpr int NROW = B * M * K;     // 524288 rows through the MLP

#define DEVFN static __device__ __forceinline__

// ---------------------------------------------------------------- transpose
__global__ __launch_bounds__(256) void transpose_kernel(
    const float* __restrict__ P, const float* __restrict__ F,
    float4* __restrict__ pts4, float* __restrict__ ft)
{
  int g = blockIdx.x * 256 + threadIdx.x;        // 0 .. B*N-1
  int b = g >> 13, i = g & (N - 1);
  const float* Pb = P + (size_t)b * 3 * N;
  pts4[g] = make_float4(Pb[i], Pb[N + i], Pb[2 * N + i], 0.f);
  const float* Fb = F + (size_t)b * 64 * N;
  float* o = ft + (size_t)g * 64;
  #pragma unroll 8
  for (int c = 0; c < 64; ++c) o[c] = Fb[(size_t)c * N + i];
}

__global__ __launch_bounds__(256) void prep_weights(
    const float* __restrict__ W0, const float* __restrict__ W1,
    const float* __restrict__ W2,
    float* __restrict__ w0T, float* __restrict__ w1T, float* __restrict__ w2T)
{
  int t = threadIdx.x;
  for (int x = t; x < 67 * 64; x += 256) { int k = x >> 6, o = x & 63;  w0T[x] = W0[o * 67 + k]; }
  for (int x = t; x < 64 * 64; x += 256) { int k = x >> 6, o = x & 63;  w1T[x] = W1[o * 64 + k]; }
  for (int x = t; x < 64 * 128; x += 256){ int k = x >> 7, o = x & 127; w2T[x] = W2[o * 64 + k]; }
}

// ---------------------------------------------------------------- FPS
// One block per batch; 256 threads (4 waves = 1/SIMD), 32 points/thread in
// registers. Exact IEEE distance; argmax tie-break = lowest index.
// Selection packed into u64 key = (float_bits(maxmin) << 32) | ~idx :
// distances are >=0 so bit pattern compares like the float; u64 max =
// (max value, min index on tie) exactly. Winner coords come from a float4
// LDS copy of the cloud (128 KB); cross-wave reduce is one ds_read_b128
// of the 4 packed partials. 4 waves halves DS-pipe butterfly cost vs 8.
constexpr int FPS_T = 256;
constexpr int FPS_PT = N / FPS_T;   // 32

__global__ __launch_bounds__(256) void fps_kernel(
    const float* __restrict__ P, float4* __restrict__ q4, float* __restrict__ out_q)
{
  __shared__ float4 sp4[N];                             // 128 KB point table
  __shared__ __align__(32) unsigned long long partial[2][4];
  const int b = blockIdx.x, tid = threadIdx.x;
  const float* Pb = P + (size_t)b * 3 * N;

  float px[FPS_PT], py[FPS_PT], pz[FPS_PT], mind[FPS_PT];
  #pragma unroll
  for (int j = 0; j < FPS_PT; ++j) {
    int i = tid + j * FPS_T;
    px[j] = Pb[i]; py[j] = Pb[N + i]; pz[j] = Pb[2 * N + i];
    sp4[i] = make_float4(px[j], py[j], pz[j], 0.f);
    mind[j] = 1e10f;
  }
  __syncthreads();

  float cx = Pb[0], cy = Pb[N], cz = Pb[2 * N];   // centroid 0 = point 0
  if (tid == 0) {
    out_q[b * 3 * M + 0] = cx; out_q[b * 3 * M + M] = cy; out_q[b * 3 * M + 2 * M] = cz;
    q4[b * M] = make_float4(cx, cy, cz, 0.f);
  }

  for (int s = 1; s < M; ++s) {
    // phase A: exact min-update + per-thread argmax (value, lowest idx)
    float bv = -1.f; int bi = 0;
    #pragma unroll
    for (int j = 0; j < FPS_PT; ++j) {
      float dx = __fsub_rn(px[j], cx), dy = __fsub_rn(py[j], cy), dz = __fsub_rn(pz[j], cz);
      float d  = __fadd_rn(__fadd_rn(__fmul_rn(dx, dx), __fmul_rn(dy, dy)), __fmul_rn(dz, dz));
      float mm = fminf(mind[j], d);
      mind[j] = mm;
      bool t = mm > bv;                  // strict > keeps lowest index (j ascending)
      bv = t ? mm : bv;
      bi = t ? tid + j * FPS_T : bi;
    }
    // pack and butterfly-reduce within wave
    unsigned long long key =
        ((unsigned long long)__float_as_uint(bv) << 32) | (unsigned int)(~bi);
    #pragma unroll
    for (int mask = 1; mask < 64; mask <<= 1) {
      unsigned long long o = __shfl_xor(key, mask);
      key = (o > key) ? o : key;
    }
    const int buf = s & 1;
    if ((tid & 63) == 0) partial[buf][tid >> 6] = key;
    __syncthreads();
    // all threads reduce the 4 wave partials (one 32B broadcast read)
    unsigned long long k0 = partial[buf][0];
    #pragma unroll
    for (int t = 1; t < 4; ++t) {
      unsigned long long o = partial[buf][t];
      k0 = (o > k0) ? o : k0;
    }
    const int widx = (int)(~(unsigned int)(k0 & 0xFFFFFFFFull));
    const float4 c = sp4[widx];
    cx = c.x; cy = c.y; cz = c.z;
    if (tid == 0) {
      out_q[b * 3 * M + s] = cx; out_q[b * 3 * M + M + s] = cy; out_q[b * 3 * M + 2 * M + s] = cz;
      q4[b * M + s] = make_float4(cx, cy, cz, 0.f);
    }
  }
}

// ---------------------------------------------------------------- ball query
// One wave per centroid: first K in-radius indices ascending; pad with first.
__global__ __launch_bounds__(256) void ballquery_kernel(
    const float4* __restrict__ pts4, const float4* __restrict__ q4, int* __restrict__ nbr)
{
  __shared__ int slot[4][K];
  const int wv = threadIdx.x >> 6, lane = threadIdx.x & 63;
  const int qid = blockIdx.x * 4 + wv;
  const int b = qid >> 11;
  const float4 qc = q4[qid];
  const float4* pb = pts4 + (size_t)b * N;
  const float r2 = 0.04f;                 // float(0.2**2), strict <
  int count = 0;
  for (int c0 = 0; c0 < N; c0 += 64) {
    float4 p = pb[c0 + lane];
    float dx = __fsub_rn(p.x, qc.x), dy = __fsub_rn(p.y, qc.y), dz = __fsub_rn(p.z, qc.z);
    float d2 = __fadd_rn(__fadd_rn(__fmul_rn(dx, dx), __fmul_rn(dy, dy)), __fmul_rn(dz, dz));
    bool in = d2 < r2;
    unsigned long long mask = __ballot(in);
    int pos = count + (int)__popcll(mask & ((1ull << lane) - 1ull));
    if (in && pos < K) slot[wv][pos] = c0 + lane;
    count += (int)__popcll(mask);
    if (count >= K) break;
  }
  __syncthreads();
  int valid = count < K ? count : K;
  int v = 0;
  if (valid > 0) {
    int first = slot[wv][0];
    v = (lane < valid) ? slot[wv][lane] : first;
  }
  nbr[(size_t)qid * K + lane] = v;
}

// ---------------------------------------------------------------- MLP chain
// One wave per (b,m): 64 rows. Thread tile 8 rows x 8 channels.
// x tile in LDS [k][row]; weights (pre-transposed k-major) from global/L2.
DEVFN void conv_tile(float acc[8][8], const float (&xt)[C0 + 1][64],
                     const float* __restrict__ wT, int KK, int OC, int choff, int rg)
{
  #pragma unroll
  for (int i = 0; i < 8; ++i)
    #pragma unroll
    for (int j = 0; j < 8; ++j) acc[i][j] = 0.f;
  for (int k = 0; k < KK; ++k) {
    const float4 xa = *(const float4*)&xt[k][rg * 8];
    const float4 xb = *(const float4*)&xt[k][rg * 8 + 4];
    const float4 wa = *(const float4*)(wT + (size_t)k * OC + choff);
    const float4 wb = *(const float4*)(wT + (size_t)k * OC + choff + 4);
    const float xs[8] = {xa.x, xa.y, xa.z, xa.w, xb.x, xb.y, xb.z, xb.w};
    const float wv[8] = {wa.x, wa.y, wa.z, wa.w, wb.x, wb.y, wb.z, wb.w};
    #pragma unroll
    for (int i = 0; i < 8; ++i)
      #pragma unroll
      for (int j = 0; j < 8; ++j) acc[i][j] = fmaf(xs[i], wv[j], acc[i][j]);
  }
}

DEVFN void bn_relu_store(const float acc[8][8], const float* __restrict__ sc,
                         const float* __restrict__ sh, int choff, int rg,
                         float (&xt)[C0 + 1][64])
{
  float4 s0 = *(const float4*)(sc + choff), s1 = *(const float4*)(sc + choff + 4);
  float4 h0 = *(const float4*)(sh + choff), h1 = *(const float4*)(sh + choff + 4);
  const float scv[8] = {s0.x, s0.y, s0.z, s0.w, s1.x, s1.y, s1.z, s1.w};
  const float shv[8] = {h0.x, h0.y, h0.z, h0.w, h1.x, h1.y, h1.z, h1.w};
  __syncthreads();   // all lanes done reading xt
  #pragma unroll
  for (int j = 0; j < 8; ++j) {
    float4 a, b;
    a.x = fmaxf(fmaf(acc[0][j], scv[j], shv[j]), 0.f);
    a.y = fmaxf(fmaf(acc[1][j], scv[j], shv[j]), 0.f);
    a.z = fmaxf(fmaf(acc[2][j], scv[j], shv[j]), 0.f);
    a.w = fmaxf(fmaf(acc[3][j], scv[j], shv[j]), 0.f);
    b.x = fmaxf(fmaf(acc[4][j], scv[j], shv[j]), 0.f);
    b.y = fmaxf(fmaf(acc[5][j], scv[j], shv[j]), 0.f);
    b.z = fmaxf(fmaf(acc[6][j], scv[j], shv[j]), 0.f);
    b.w = fmaxf(fmaf(acc[7][j], scv[j], shv[j]), 0.f);
    *(float4*)&xt[choff + j][rg * 8]     = a;
    *(float4*)&xt[choff + j][rg * 8 + 4] = b;
  }
  __syncthreads();   // writes visible before next conv
}

DEVFN void stats_tile(const float acc[8][8], int chbase, int lane, int qid,
                      float* __restrict__ Psum, float* __restrict__ Psq)
{
  #pragma unroll
  for (int j = 0; j < 8; ++j) {
    float s = 0.f, q = 0.f;
    #pragma unroll
    for (int i = 0; i < 8; ++i) { s += acc[i][j]; q = fmaf(acc[i][j], acc[i][j], q); }
    s += __shfl_xor(s, 8);  q += __shfl_xor(q, 8);
    s += __shfl_xor(s, 16); q += __shfl_xor(q, 16);
    s += __shfl_xor(s, 32); q += __shfl_xor(q, 32);
    if ((lane >> 3) == 0) {
      Psum[(size_t)(chbase + j) * NB_CHAIN + qid] = s;
      Psq [(size_t)(chbase + j) * NB_CHAIN + qid] = q;
    }
  }
}

DEVFN void maxpool_out(const float acc[8][8], const float* __restrict__ sc,
                       const float* __restrict__ sh, int chbase, int lane,
                       int b, int m, float* __restrict__ out1)
{
  float4 s0 = *(const float4*)(sc + chbase), s1 = *(const float4*)(sc + chbase + 4);
  float4 h0 = *(const float4*)(sh + chbase), h1 = *(const float4*)(sh + chbase + 4);
  const float scv[8] = {s0.x, s0.y, s0.z, s0.w, s1.x, s1.y, s1.z, s1.w};
  const float shv[8] = {h0.x, h0.y, h0.z, h0.w, h1.x, h1.y, h1.z, h1.w};
  #pragma unroll
  for (int j = 0; j < 8; ++j) {
    float mx = fmaxf(fmaf(acc[0][j], scv[j], shv[j]), 0.f);
    #pragma unroll
    for (int i = 1; i < 8; ++i)
      mx = fmaxf(mx, fmaxf(fmaf(acc[i][j], scv[j], shv[j]), 0.f));
    mx = fmaxf(mx, __shfl_xor(mx, 8));
    mx = fmaxf(mx, __shfl_xor(mx, 16));
    mx = fmaxf(mx, __shfl_xor(mx, 32));
    if ((lane >> 3) == 0)
      out1[((size_t)b * 128 + chbase + j) * M + m] = mx;
  }
}

template <int PHASE>
__global__ __launch_bounds__(64) void chain_kernel(
    const float4* __restrict__ pts4, const float* __restrict__ ft,
    const float4* __restrict__ q4, const int* __restrict__ nbr,
    const float* __restrict__ w0T, const float* __restrict__ w1T, const float* __restrict__ w2T,
    const float* __restrict__ sc1, const float* __restrict__ sh1,
    const float* __restrict__ sc2, const float* __restrict__ sh2,
    const float* __restrict__ sc3, const float* __restrict__ sh3,
    float* __restrict__ Psum, float* __restrict__ Psq, float* __restrict__ out1)
{
  __shared__ float xt[C0 + 1][64];            // [k][row], 17.4 KB
  const int qid = blockIdx.x;
  const int b = qid >> 11, m = qid & (M - 1);
  const int lane = threadIdx.x;
  const int rg = lane >> 3, cg = lane & 7;

  // stage x0 = [rel(3), feats(64)] transposed into LDS
  const int i = nbr[(size_t)qid * K + lane];
  const float4 qc = q4[qid];
  const float4 p = pts4[(size_t)b * N + i];
  xt[0][lane] = p.x - qc.x;
  xt[1][lane] = p.y - qc.y;
  xt[2][lane] = p.z - qc.z;
  const float4* fr = (const float4*)(ft + (size_t)(b * N + i) * 64);
  #pragma unroll
  for (int c = 0; c < 16; ++c) {
    float4 f = fr[c];
    xt[3 + 4 * c + 0][lane] = f.x;
    xt[3 + 4 * c + 1][lane] = f.y;
    xt[3 + 4 * c + 2][lane] = f.z;
    xt[3 + 4 * c + 3][lane] = f.w;
  }
  __syncthreads();

  float acc[8][8];
  conv_tile(acc, xt, w0T, 67, 64, cg * 8, rg);              // conv1
  if (PHASE == 1) { stats_tile(acc, cg * 8, lane, qid, Psum, Psq); return; }

  bn_relu_store(acc, sc1, sh1, cg * 8, rg, xt);             // h1 -> LDS
  conv_tile(acc, xt, w1T, 64, 64, cg * 8, rg);              // conv2
  if (PHASE == 2) { stats_tile(acc, cg * 8, lane, qid, Psum, Psq); return; }

  bn_relu_store(acc, sc2, sh2, cg * 8, rg, xt);             // h2 -> LDS
  conv_tile(acc, xt, w2T, 64, 128, cg * 8, rg);             // conv3 half 0
  if (PHASE == 3) stats_tile(acc, cg * 8, lane, qid, Psum, Psq);
  else            maxpool_out(acc, sc3, sh3, cg * 8, lane, b, m, out1);
  conv_tile(acc, xt, w2T, 64, 128, 64 + cg * 8, rg);        // conv3 half 1
  if (PHASE == 3) stats_tile(acc, 64 + cg * 8, lane, qid, Psum, Psq);
  else            maxpool_out(acc, sc3, sh3, 64 + cg * 8, lane, b, m, out1);
}

// ---------------------------------------------------------------- stats reduce
__global__ __launch_bounds__(256) void reduce_stats(
    const float* __restrict__ Psum, const float* __restrict__ Psq,
    const float* __restrict__ g, const float* __restrict__ beta,
    float* __restrict__ scale, float* __restrict__ shift)
{
  __shared__ float ls[256], lq[256];
  const int o = blockIdx.x, t = threadIdx.x;
  float s = 0.f, q = 0.f;
  for (int x = t; x < NB_CHAIN; x += 256) {
    s += Psum[(size_t)o * NB_CHAIN + x];
    q += Psq [(size_t)o * NB_CHAIN + x];
  }
  ls[t] = s; lq[t] = q;
  __syncthreads();
  for (int st = 128; st > 0; st >>= 1) {
    if (t < st) { ls[t] += ls[t + st]; lq[t] += lq[t + st]; }
    __syncthreads();
  }
  if (t == 0) {
    const float inv = 1.f / (float)NROW;
    float mu = ls[0] * inv;
    float var = lq[0] * inv - mu * mu;
    float scv = g[o] / sqrtf(var + 1e-5f);
    scale[o] = scv;
    shift[o] = beta[o] - mu * scv;
  }
}

// ---------------------------------------------------------------- launcher
extern "C" void kernel_launch(void* const* d_in, const int* in_sizes, int n_in,
                              void* d_out, int out_size, void* d_ws, size_t ws_size,
                              hipStream_t stream)
{
  const float* P  = (const float*)d_in[0];
  const float* F  = (const float*)d_in[1];
  const float* W0 = (const float*)d_in[2];
  const float* g0 = (const float*)d_in[3];
  const float* b0 = (const float*)d_in[4];
  const float* W1 = (const float*)d_in[5];
  const float* g1 = (const float*)d_in[6];
  const float* b1 = (const float*)d_in[7];
  const float* W2 = (const float*)d_in[8];
  const float* g2 = (const float*)d_in[9];
  const float* b2 = (const float*)d_in[10];

  float* out_q = (float*)d_out;           // (B,3,M)
  float* out_f = out_q + B * 3 * M;       // (B,128,M)

  char* w = (char*)d_ws;
  size_t off = 0;
  auto alloc = [&](size_t bytes) -> void* {
    off = (off + 255) & ~(size_t)255;
    void* p = w + off;
    off += bytes;
    return p;
  };
  float4* pts4 = (float4*)alloc((size_t)B * N * sizeof(float4));
  float*  ft   = (float*) alloc((size_t)B * N * 64 * 4);
  float*  w0T  = (float*) alloc(68 * 64 * 4);
  float*  w1T  = (float*) alloc(64 * 64 * 4);
  float*  w2T  = (float*) alloc(64 * 128 * 4);
  float4* q4   = (float4*)alloc((size_t)B * M * sizeof(float4));
  int*    nbr  = (int*)   alloc((size_t)B * M * K * 4);
  float*  Psum = (float*) alloc((size_t)128 * NB_CHAIN * 4);
  float*  Psq  = (float*) alloc((size_t)128 * NB_CHAIN * 4);
  float*  bnp  = (float*) alloc(6 * 128 * 4);
  float *sc1 = bnp, *sh1 = bnp + 128, *sc2 = bnp + 256, *sh2 = bnp + 384,
        *sc3 = bnp + 512, *sh3 = bnp + 640;
  (void)ws_size; (void)in_sizes; (void)n_in; (void)out_size;

  transpose_kernel<<<B * N / 256, 256, 0, stream>>>(P, F, pts4, ft);
  prep_weights<<<1, 256, 0, stream>>>(W0, W1, W2, w0T, w1T, w2T);
  fps_kernel<<<B, FPS_T, 0, stream>>>(P, q4, out_q);
  ballquery_kernel<<<B * M / 4, 256, 0, stream>>>(pts4, q4, nbr);

  chain_kernel<1><<<NB_CHAIN, 64, 0, stream>>>(pts4, ft, q4, nbr, w0T, w1T, w2T,
      sc1, sh1, sc2, sh2, sc3, sh3, Psum, Psq, out_f);
  reduce_stats<<<64, 256, 0, stream>>>(Psum, Psq, g0, b0, sc1, sh1);
  chain_kernel<2><<<NB_CHAIN, 64, 0, stream>>>(pts4, ft, q4, nbr, w0T, w1T, w2T,
      sc1, sh1, sc2, sh2, sc3, sh3, Psum, Psq, out_f);
  reduce_stats<<<64, 256, 0, stream>>>(Psum, Psq, g1, b1, sc2, sh2);
  chain_kernel<3><<<NB_CHAIN, 64, 0, stream>>>(pts4, ft, q4, nbr, w0T, w1T, w2T,
      sc1, sh1, sc2, sh2, sc3, sh3, Psum, Psq, out_f);
  reduce_stats<<<128, 256, 0, stream>>>(Psum, Psq, g2, b2, sc3, sh3);
  chain_kernel<4><<<NB_CHAIN, 64, 0, stream>>>(pts4, ft, q4, nbr, w0T, w1T, w2T,
      sc1, sh1, sc2, sh2, sc3, sh3, Psum, Psq, out_f);
}

// Round 5
// 3045.258 us; speedup vs baseline: 1.0709x; 1.0709x over previous
//
#include <hip/hip_runtime.h>
#include <math.h>

// PointNet++ SetAbstraction for MI355X.
// B=4 N=8192 M=2048 K=64 C_IN=64, dims 67->64->64->128, radius 0.2.
// Exactness-critical paths (FPS argmax, ball-query radius test) use
// __f*_rn intrinsics to bit-match plain IEEE mul/add (no FMA contraction).

constexpr int B = 4, N = 8192, M = 2048, K = 64;
constexpr int C0 = 67;              // 3 + 64 input channels
constexpr int NB_CHAIN = B * M;     // one block per (b,m) = 8192
constexpr int NROW = B * M * K;     // 524288 rows through the MLP

#define DEVFN static __device__ __forceinline__

// ---------------------------------------------------------------- transpose
__global__ __launch_bounds__(256) void transpose_kernel(
    const float* __restrict__ P, const float* __restrict__ F,
    float4* __restrict__ pts4, float* __restrict__ ft)
{
  int g = blockIdx.x * 256 + threadIdx.x;        // 0 .. B*N-1
  int b = g >> 13, i = g & (N - 1);
  const float* Pb = P + (size_t)b * 3 * N;
  pts4[g] = make_float4(Pb[i], Pb[N + i], Pb[2 * N + i], 0.f);
  const float* Fb = F + (size_t)b * 64 * N;
  float* o = ft + (size_t)g * 64;
  #pragma unroll 8
  for (int c = 0; c < 64; ++c) o[c] = Fb[(size_t)c * N + i];
}

__global__ __launch_bounds__(256) void prep_weights(
    const float* __restrict__ W0, const float* __restrict__ W1,
    const float* __restrict__ W2,
    float* __restrict__ w0T, float* __restrict__ w1T, float* __restrict__ w2T)
{
  int t = threadIdx.x;
  for (int x = t; x < 67 * 64; x += 256) { int k = x >> 6, o = x & 63;  w0T[x] = W0[o * 67 + k]; }
  for (int x = t; x < 64 * 64; x += 256) { int k = x >> 6, o = x & 63;  w1T[x] = W1[o * 64 + k]; }
  for (int x = t; x < 64 * 128; x += 256){ int k = x >> 7, o = x & 127; w2T[x] = W2[o * 64 + k]; }
}

// ---------------------------------------------------------------- FPS
// One block per batch; 512 threads (2 waves/SIMD for latency hiding).
// Thread t owns CONTIGUOUS points [16t, 16t+16) -> lane order == index
// order, so value-tie -> lowest lane wins. Wave reduce: 6x f32 max
// shuffles + ballot + one index shuffle. Cross-wave: u64 key
// (value_bits<<32 | ~idx), max = (max value, min index). NO global
// memory ops inside the loop (they force a vmcnt(0) drain at each
// __syncthreads) -- winner indices buffered in LDS, bulk write at end.
constexpr int FPS_T = 512;
constexpr int FPS_PT = N / FPS_T;   // 16

__global__ __launch_bounds__(512) void fps_kernel(
    const float* __restrict__ P, float4* __restrict__ q4, float* __restrict__ out_q)
{
  __shared__ float4 sp4[N];                             // 128 KB point table
  __shared__ __align__(16) unsigned long long partial[2][8];
  __shared__ unsigned short swidx[M];                   // 4 KB winner idx
  const int b = blockIdx.x, tid = threadIdx.x;
  const float* Pb = P + (size_t)b * 3 * N;

  float px[FPS_PT], py[FPS_PT], pz[FPS_PT], mind[FPS_PT];
  #pragma unroll
  for (int j = 0; j < FPS_PT; ++j) {
    int i = tid * FPS_PT + j;                           // contiguous block
    px[j] = Pb[i]; py[j] = Pb[N + i]; pz[j] = Pb[2 * N + i];
    sp4[i] = make_float4(px[j], py[j], pz[j], 0.f);
    mind[j] = 1e10f;
  }
  if (tid == 0) swidx[0] = 0;                           // centroid 0 = point 0
  __syncthreads();

  float cx = Pb[0], cy = Pb[N], cz = Pb[2 * N];

  for (int s = 1; s < M; ++s) {
    // phase A: exact min-update + per-thread argmax (value, lowest idx)
    float bv = -1.f; int bi = 0;
    #pragma unroll
    for (int j = 0; j < FPS_PT; ++j) {
      float dx = __fsub_rn(px[j], cx), dy = __fsub_rn(py[j], cy), dz = __fsub_rn(pz[j], cz);
      float d  = __fadd_rn(__fadd_rn(__fmul_rn(dx, dx), __fmul_rn(dy, dy)), __fmul_rn(dz, dz));
      float mm = fminf(mind[j], d);
      mind[j] = mm;
      bool tk = mm > bv;                 // strict > keeps lowest index (j ascending)
      bv = tk ? mm : bv;
      bi = tk ? tid * FPS_PT + j : bi;
    }
    // wave reduce: value-only max butterfly (6 x 32-bit shuffles)
    float wv = bv;
    #pragma unroll
    for (int mask = 1; mask < 64; mask <<= 1)
      wv = fmaxf(wv, __shfl_xor(wv, mask));
    // lowest tied lane holds the smallest candidate index
    unsigned long long tied = __ballot(bv == wv);
    int wl = __ffsll(tied) - 1;
    int wi = __shfl(bi, wl);
    unsigned long long key =
        ((unsigned long long)__float_as_uint(wv) << 32) | (unsigned int)(~wi);
    const int buf = s & 1;
    if ((tid & 63) == 0) partial[buf][tid >> 6] = key;
    __syncthreads();
    // all threads reduce the 8 wave partials redundantly
    unsigned long long k0 = partial[buf][0];
    #pragma unroll
    for (int w = 1; w < 8; ++w) {
      unsigned long long o = partial[buf][w];
      k0 = (o > k0) ? o : k0;
    }
    const int widx = (int)(~(unsigned int)(k0 & 0xFFFFFFFFull));
    const float4 c = sp4[widx];
    cx = c.x; cy = c.y; cz = c.z;
    if (tid == 0) swidx[s] = (unsigned short)widx;
  }
  __syncthreads();
  // bulk write-out of the selected centroids
  for (int s = tid; s < M; s += FPS_T) {
    const float4 c = sp4[swidx[s]];
    q4[b * M + s] = c;
    out_q[b * 3 * M + s]         = c.x;
    out_q[b * 3 * M + M + s]     = c.y;
    out_q[b * 3 * M + 2 * M + s] = c.z;
  }
}

// ---------------------------------------------------------------- ball query
// One wave per centroid: first K in-radius indices ascending; pad with first.
__global__ __launch_bounds__(256) void ballquery_kernel(
    const float4* __restrict__ pts4, const float4* __restrict__ q4, int* __restrict__ nbr)
{
  __shared__ int slot[4][K];
  const int wv = threadIdx.x >> 6, lane = threadIdx.x & 63;
  const int qid = blockIdx.x * 4 + wv;
  const int b = qid >> 11;
  const float4 qc = q4[qid];
  const float4* pb = pts4 + (size_t)b * N;
  const float r2 = 0.04f;                 // float(0.2**2), strict <
  int count = 0;
  for (int c0 = 0; c0 < N; c0 += 64) {
    float4 p = pb[c0 + lane];
    float dx = __fsub_rn(p.x, qc.x), dy = __fsub_rn(p.y, qc.y), dz = __fsub_rn(p.z, qc.z);
    float d2 = __fadd_rn(__fadd_rn(__fmul_rn(dx, dx), __fmul_rn(dy, dy)), __fmul_rn(dz, dz));
    bool in = d2 < r2;
    unsigned long long mask = __ballot(in);
    int pos = count + (int)__popcll(mask & ((1ull << lane) - 1ull));
    if (in && pos < K) slot[wv][pos] = c0 + lane;
    count += (int)__popcll(mask);
    if (count >= K) break;
  }
  __syncthreads();
  int valid = count < K ? count : K;
  int v = 0;
  if (valid > 0) {
    int first = slot[wv][0];
    v = (lane < valid) ? slot[wv][lane] : first;
  }
  nbr[(size_t)qid * K + lane] = v;
}

// ---------------------------------------------------------------- MLP chain
// One wave per (b,m): 64 rows. Thread tile 8 rows x 8 channels.
// x tile in LDS [k][row]; weights (pre-transposed k-major) from global/L2.
DEVFN void conv_tile(float acc[8][8], const float (&xt)[C0 + 1][64],
                     const float* __restrict__ wT, int KK, int OC, int choff, int rg)
{
  #pragma unroll
  for (int i = 0; i < 8; ++i)
    #pragma unroll
    for (int j = 0; j < 8; ++j) acc[i][j] = 0.f;
  for (int k = 0; k < KK; ++k) {
    const float4 xa = *(const float4*)&xt[k][rg * 8];
    const float4 xb = *(const float4*)&xt[k][rg * 8 + 4];
    const float4 wa = *(const float4*)(wT + (size_t)k * OC + choff);
    const float4 wb = *(const float4*)(wT + (size_t)k * OC + choff + 4);
    const float xs[8] = {xa.x, xa.y, xa.z, xa.w, xb.x, xb.y, xb.z, xb.w};
    const float wv[8] = {wa.x, wa.y, wa.z, wa.w, wb.x, wb.y, wb.z, wb.w};
    #pragma unroll
    for (int i = 0; i < 8; ++i)
      #pragma unroll
      for (int j = 0; j < 8; ++j) acc[i][j] = fmaf(xs[i], wv[j], acc[i][j]);
  }
}

DEVFN void bn_relu_store(const float acc[8][8], const float* __restrict__ sc,
                         const float* __restrict__ sh, int choff, int rg,
                         float (&xt)[C0 + 1][64])
{
  float4 s0 = *(const float4*)(sc + choff), s1 = *(const float4*)(sc + choff + 4);
  float4 h0 = *(const float4*)(sh + choff), h1 = *(const float4*)(sh + choff + 4);
  const float scv[8] = {s0.x, s0.y, s0.z, s0.w, s1.x, s1.y, s1.z, s1.w};
  const float shv[8] = {h0.x, h0.y, h0.z, h0.w, h1.x, h1.y, h1.z, h1.w};
  __syncthreads();   // all lanes done reading xt
  #pragma unroll
  for (int j = 0; j < 8; ++j) {
    float4 a, b;
    a.x = fmaxf(fmaf(acc[0][j], scv[j], shv[j]), 0.f);
    a.y = fmaxf(fmaf(acc[1][j], scv[j], shv[j]), 0.f);
    a.z = fmaxf(fmaf(acc[2][j], scv[j], shv[j]), 0.f);
    a.w = fmaxf(fmaf(acc[3][j], scv[j], shv[j]), 0.f);
    b.x = fmaxf(fmaf(acc[4][j], scv[j], shv[j]), 0.f);
    b.y = fmaxf(fmaf(acc[5][j], scv[j], shv[j]), 0.f);
    b.z = fmaxf(fmaf(acc[6][j], scv[j], shv[j]), 0.f);
    b.w = fmaxf(fmaf(acc[7][j], scv[j], shv[j]), 0.f);
    *(float4*)&xt[choff + j][rg * 8]     = a;
    *(float4*)&xt[choff + j][rg * 8 + 4] = b;
  }
  __syncthreads();   // writes visible before next conv
}

DEVFN void stats_tile(const float acc[8][8], int chbase, int lane, int qid,
                      float* __restrict__ Psum, float* __restrict__ Psq)
{
  #pragma unroll
  for (int j = 0; j < 8; ++j) {
    float s = 0.f, q = 0.f;
    #pragma unroll
    for (int i = 0; i < 8; ++i) { s += acc[i][j]; q = fmaf(acc[i][j], acc[i][j], q); }
    s += __shfl_xor(s, 8);  q += __shfl_xor(q, 8);
    s += __shfl_xor(s, 16); q += __shfl_xor(q, 16);
    s += __shfl_xor(s, 32); q += __shfl_xor(q, 32);
    if ((lane >> 3) == 0) {
      Psum[(size_t)(chbase + j) * NB_CHAIN + qid] = s;
      Psq [(size_t)(chbase + j) * NB_CHAIN + qid] = q;
    }
  }
}

DEVFN void maxpool_out(const float acc[8][8], const float* __restrict__ sc,
                       const float* __restrict__ sh, int chbase, int lane,
                       int b, int m, float* __restrict__ out1)
{
  float4 s0 = *(const float4*)(sc + chbase), s1 = *(const float4*)(sc + chbase + 4);
  float4 h0 = *(const float4*)(sh + chbase), h1 = *(const float4*)(sh + chbase + 4);
  const float scv[8] = {s0.x, s0.y, s0.z, s0.w, s1.x, s1.y, s1.z, s1.w};
  const float shv[8] = {h0.x, h0.y, h0.z, h0.w, h1.x, h1.y, h1.z, h1.w};
  #pragma unroll
  for (int j = 0; j < 8; ++j) {
    float mx = fmaxf(fmaf(acc[0][j], scv[j], shv[j]), 0.f);
    #pragma unroll
    for (int i = 1; i < 8; ++i)
      mx = fmaxf(mx, fmaxf(fmaf(acc[i][j], scv[j], shv[j]), 0.f));
    mx = fmaxf(mx, __shfl_xor(mx, 8));
    mx = fmaxf(mx, __shfl_xor(mx, 16));
    mx = fmaxf(mx, __shfl_xor(mx, 32));
    if ((lane >> 3) == 0)
      out1[((size_t)b * 128 + chbase + j) * M + m] = mx;
  }
}

template <int PHASE>
__global__ __launch_bounds__(64) void chain_kernel(
    const float4* __restrict__ pts4, const float* __restrict__ ft,
    const float4* __restrict__ q4, const int* __restrict__ nbr,
    const float* __restrict__ w0T, const float* __restrict__ w1T, const float* __restrict__ w2T,
    const float* __restrict__ sc1, const float* __restrict__ sh1,
    const float* __restrict__ sc2, const float* __restrict__ sh2,
    const float* __restrict__ sc3, const float* __restrict__ sh3,
    float* __restrict__ Psum, float* __restrict__ Psq, float* __restrict__ out1)
{
  __shared__ float xt[C0 + 1][64];            // [k][row], 17.4 KB
  const int qid = blockIdx.x;
  const int b = qid >> 11, m = qid & (M - 1);
  const int lane = threadIdx.x;
  const int rg = lane >> 3, cg = lane & 7;

  // stage x0 = [rel(3), feats(64)] transposed into LDS
  const int i = nbr[(size_t)qid * K + lane];
  const float4 qc = q4[qid];
  const float4 p = pts4[(size_t)b * N + i];
  xt[0][lane] = p.x - qc.x;
  xt[1][lane] = p.y - qc.y;
  xt[2][lane] = p.z - qc.z;
  const float4* fr = (const float4*)(ft + (size_t)(b * N + i) * 64);
  #pragma unroll
  for (int c = 0; c < 16; ++c) {
    float4 f = fr[c];
    xt[3 + 4 * c + 0][lane] = f.x;
    xt[3 + 4 * c + 1][lane] = f.y;
    xt[3 + 4 * c + 2][lane] = f.z;
    xt[3 + 4 * c + 3][lane] = f.w;
  }
  __syncthreads();

  float acc[8][8];
  conv_tile(acc, xt, w0T, 67, 64, cg * 8, rg);              // conv1
  if (PHASE == 1) { stats_tile(acc, cg * 8, lane, qid, Psum, Psq); return; }

  bn_relu_store(acc, sc1, sh1, cg * 8, rg, xt);             // h1 -> LDS
  conv_tile(acc, xt, w1T, 64, 64, cg * 8, rg);              // conv2
  if (PHASE == 2) { stats_tile(acc, cg * 8, lane, qid, Psum, Psq); return; }

  bn_relu_store(acc, sc2, sh2, cg * 8, rg, xt);             // h2 -> LDS
  conv_tile(acc, xt, w2T, 64, 128, cg * 8, rg);             // conv3 half 0
  if (PHASE == 3) stats_tile(acc, cg * 8, lane, qid, Psum, Psq);
  else            maxpool_out(acc, sc3, sh3, cg * 8, lane, b, m, out1);
  conv_tile(acc, xt, w2T, 64, 128, 64 + cg * 8, rg);        // conv3 half 1
  if (PHASE == 3) stats_tile(acc, 64 + cg * 8, lane, qid, Psum, Psq);
  else            maxpool_out(acc, sc3, sh3, 64 + cg * 8, lane, b, m, out1);
}

// ---------------------------------------------------------------- stats reduce
__global__ __launch_bounds__(256) void reduce_stats(
    const float* __restrict__ Psum, const float* __restrict__ Psq,
    const float* __restrict__ g, const float* __restrict__ beta,
    float* __restrict__ scale, float* __restrict__ shift)
{
  __shared__ float ls[256], lq[256];
  const int o = blockIdx.x, t = threadIdx.x;
  float s = 0.f, q = 0.f;
  for (int x = t; x < NB_CHAIN; x += 256) {
    s += Psum[(size_t)o * NB_CHAIN + x];
    q += Psq [(size_t)o * NB_CHAIN + x];
  }
  ls[t] = s; lq[t] = q;
  __syncthreads();
  for (int st = 128; st > 0; st >>= 1) {
    if (t < st) { ls[t] += ls[t + st]; lq[t] += lq[t + st]; }
    __syncthreads();
  }
  if (t == 0) {
    const float inv = 1.f / (float)NROW;
    float mu = ls[0] * inv;
    float var = lq[0] * inv - mu * mu;
    float scv = g[o] / sqrtf(var + 1e-5f);
    scale[o] = scv;
    shift[o] = beta[o] - mu * scv;
  }
}

// ---------------------------------------------------------------- launcher
extern "C" void kernel_launch(void* const* d_in, const int* in_sizes, int n_in,
                              void* d_out, int out_size, void* d_ws, size_t ws_size,
                              hipStream_t stream)
{
  const float* P  = (const float*)d_in[0];
  const float* F  = (const float*)d_in[1];
  const float* W0 = (const float*)d_in[2];
  const float* g0 = (const float*)d_in[3];
  const float* b0 = (const float*)d_in[4];
  const float* W1 = (const float*)d_in[5];
  const float* g1 = (const float*)d_in[6];
  const float* b1 = (const float*)d_in[7];
  const float* W2 = (const float*)d_in[8];
  const float* g2 = (const float*)d_in[9];
  const float* b2 = (const float*)d_in[10];

  float* out_q = (float*)d_out;           // (B,3,M)
  float* out_f = out_q + B * 3 * M;       // (B,128,M)

  char* w = (char*)d_ws;
  size_t off = 0;
  auto alloc = [&](size_t bytes) -> void* {
    off = (off + 255) & ~(size_t)255;
    void* p = w + off;
    off += bytes;
    return p;
  };
  float4* pts4 = (float4*)alloc((size_t)B * N * sizeof(float4));
  float*  ft   = (float*) alloc((size_t)B * N * 64 * 4);
  float*  w0T  = (float*) alloc(68 * 64 * 4);
  float*  w1T  = (float*) alloc(64 * 64 * 4);
  float*  w2T  = (float*) alloc(64 * 128 * 4);
  float4* q4   = (float4*)alloc((size_t)B * M * sizeof(float4));
  int*    nbr  = (int*)   alloc((size_t)B * M * K * 4);
  float*  Psum = (float*) alloc((size_t)128 * NB_CHAIN * 4);
  float*  Psq  = (float*) alloc((size_t)128 * NB_CHAIN * 4);
  float*  bnp  = (float*) alloc(6 * 128 * 4);
  float *sc1 = bnp, *sh1 = bnp + 128, *sc2 = bnp + 256, *sh2 = bnp + 384,
        *sc3 = bnp + 512, *sh3 = bnp + 640;
  (void)ws_size; (void)in_sizes; (void)n_in; (void)out_size;

  transpose_kernel<<<B * N / 256, 256, 0, stream>>>(P, F, pts4, ft);
  prep_weights<<<1, 256, 0, stream>>>(W0, W1, W2, w0T, w1T, w2T);
  fps_kernel<<<B, FPS_T, 0, stream>>>(P, q4, out_q);
  ballquery_kernel<<<B * M / 4, 256, 0, stream>>>(pts4, q4, nbr);

  chain_kernel<1><<<NB_CHAIN, 64, 0, stream>>>(pts4, ft, q4, nbr, w0T, w1T, w2T,
      sc1, sh1, sc2, sh2, sc3, sh3, Psum, Psq, out_f);
  reduce_stats<<<64, 256, 0, stream>>>(Psum, Psq, g0, b0, sc1, sh1);
  chain_kernel<2><<<NB_CHAIN, 64, 0, stream>>>(pts4, ft, q4, nbr, w0T, w1T, w2T,
      sc1, sh1, sc2, sh2, sc3, sh3, Psum, Psq, out_f);
  reduce_stats<<<64, 256, 0, stream>>>(Psum, Psq, g1, b1, sc2, sh2);
  chain_kernel<3><<<NB_CHAIN, 64, 0, stream>>>(pts4, ft, q4, nbr, w0T, w1T, w2T,
      sc1, sh1, sc2, sh2, sc3, sh3, Psum, Psq, out_f);
  reduce_stats<<<128, 256, 0, stream>>>(Psum, Psq, g2, b2, sc3, sh3);
  chain_kernel<4><<<NB_CHAIN, 64, 0, stream>>>(pts4, ft, q4, nbr, w0T, w1T, w2T,
      sc1, sh1, sc2, sh2, sc3, sh3, Psum, Psq, out_f);
}

// Round 6
// 2886.903 us; speedup vs baseline: 1.1296x; 1.0549x over previous
//
#include <hip/hip_runtime.h>
#include <math.h>

// PointNet++ SetAbstraction for MI355X.
// B=4 N=8192 M=2048 K=64 C_IN=64, dims 67->64->64->128, radius 0.2.
// Exactness-critical paths (FPS argmax, ball-query radius test) use
// __f*_rn / packed-IEEE ops to bit-match plain mul/add (no FMA contraction).

constexpr int B = 4, N = 8192, M = 2048, K = 64;
constexpr int C0 = 67;              // 3 + 64 input channels
constexpr int NB_CHAIN = B * M;     // one block per (b,m) = 8192
constexpr int NROW = B * M * K;     // 524288 rows through the MLP

#define DEVFN static __device__ __forceinline__

typedef float f32x2 __attribute__((ext_vector_type(2)));

// CDNA packed f32 (VOP3P, full-rate since gfx90a). Each half is an
// independent IEEE rn op == v_add_f32 / v_mul_f32 bit-for-bit.
DEVFN f32x2 pk_add(f32x2 a, f32x2 b) {
  f32x2 d; asm("v_pk_add_f32 %0, %1, %2" : "=v"(d) : "v"(a), "v"(b)); return d;
}
DEVFN f32x2 pk_mul(f32x2 a, f32x2 b) {
  f32x2 d; asm("v_pk_mul_f32 %0, %1, %2" : "=v"(d) : "v"(a), "v"(b)); return d;
}

// ---------------------------------------------------------------- transpose
__global__ __launch_bounds__(256) void transpose_kernel(
    const float* __restrict__ P, const float* __restrict__ F,
    float4* __restrict__ pts4, float* __restrict__ ft)
{
  int g = blockIdx.x * 256 + threadIdx.x;        // 0 .. B*N-1
  int b = g >> 13, i = g & (N - 1);
  const float* Pb = P + (size_t)b * 3 * N;
  pts4[g] = make_float4(Pb[i], Pb[N + i], Pb[2 * N + i], 0.f);
  const float* Fb = F + (size_t)b * 64 * N;
  float* o = ft + (size_t)g * 64;
  #pragma unroll 8
  for (int c = 0; c < 64; ++c) o[c] = Fb[(size_t)c * N + i];
}

__global__ __launch_bounds__(256) void prep_weights(
    const float* __restrict__ W0, const float* __restrict__ W1,
    const float* __restrict__ W2,
    float* __restrict__ w0T, float* __restrict__ w1T, float* __restrict__ w2T)
{
  int t = threadIdx.x;
  for (int x = t; x < 67 * 64; x += 256) { int k = x >> 6, o = x & 63;  w0T[x] = W0[o * 67 + k]; }
  for (int x = t; x < 64 * 64; x += 256) { int k = x >> 6, o = x & 63;  w1T[x] = W1[o * 64 + k]; }
  for (int x = t; x < 64 * 128; x += 256){ int k = x >> 7, o = x & 127; w2T[x] = W2[o * 64 + k]; }
}

// ---------------------------------------------------------------- FPS
// One block per batch; 512 threads (2 waves/SIMD). Thread t owns
// CONTIGUOUS points [16t, 16t+16), processed as 8 packed pairs:
// v_pk_add/v_pk_mul compute 2 exact IEEE distances per instruction
// (a-c done as a+(-c), bit-identical). min/argmax scalar: strict >
// with ascending index keeps lowest-index-on-tie. Wave reduce:
// value-only f32 max butterfly + ballot for the owning lane.
// Cross-wave: u64 key (value_bits<<32 | ~idx). No global ops in the
// loop (vmcnt(0) drain at barriers); bulk write at end.
constexpr int FPS_T = 512;
constexpr int FPS_PT = N / FPS_T;   // 16
constexpr int FPS_PR = FPS_PT / 2;  // 8 packed pairs

__global__ __launch_bounds__(512) void fps_kernel(
    const float* __restrict__ P, float4* __restrict__ q4, float* __restrict__ out_q)
{
  __shared__ float4 sp4[N];                             // 128 KB point table
  __shared__ __align__(16) unsigned long long partial[2][8];
  __shared__ unsigned short swidx[M];                   // 4 KB winner idx
  const int b = blockIdx.x, tid = threadIdx.x;
  const float* Pb = P + (size_t)b * 3 * N;

  f32x2 px2[FPS_PR], py2[FPS_PR], pz2[FPS_PR];
  float mind[FPS_PT];
  #pragma unroll
  for (int j = 0; j < FPS_PR; ++j) {
    int i = tid * FPS_PT + 2 * j;                       // contiguous block
    px2[j] = f32x2{Pb[i],         Pb[i + 1]};
    py2[j] = f32x2{Pb[N + i],     Pb[N + i + 1]};
    pz2[j] = f32x2{Pb[2 * N + i], Pb[2 * N + i + 1]};
    sp4[i]     = make_float4(px2[j].x, py2[j].x, pz2[j].x, 0.f);
    sp4[i + 1] = make_float4(px2[j].y, py2[j].y, pz2[j].y, 0.f);
    mind[2 * j] = 1e10f; mind[2 * j + 1] = 1e10f;
  }
  if (tid == 0) swidx[0] = 0;                           // centroid 0 = point 0
  __syncthreads();

  float cx = Pb[0], cy = Pb[N], cz = Pb[2 * N];

  for (int s = 1; s < M; ++s) {
    const f32x2 ncx = f32x2{-cx, -cx}, ncy = f32x2{-cy, -cy}, ncz = f32x2{-cz, -cz};
    float bv = -1.f; int bi = 0;
    #pragma unroll
    for (int j = 0; j < FPS_PR; ++j) {
      f32x2 dx = pk_add(px2[j], ncx);                   // p - c (exact)
      f32x2 dy = pk_add(py2[j], ncy);
      f32x2 dz = pk_add(pz2[j], ncz);
      f32x2 d  = pk_add(pk_add(pk_mul(dx, dx), pk_mul(dy, dy)), pk_mul(dz, dz));
      float m0 = fminf(mind[2 * j],     d.x); mind[2 * j]     = m0;
      float m1 = fminf(mind[2 * j + 1], d.y); mind[2 * j + 1] = m1;
      bool t0 = m0 > bv;                 // strict > keeps lowest index
      bv = t0 ? m0 : bv;
      bi = t0 ? tid * FPS_PT + 2 * j : bi;
      bool t1 = m1 > bv;
      bv = t1 ? m1 : bv;
      bi = t1 ? tid * FPS_PT + 2 * j + 1 : bi;
    }
    // wave reduce: value-only max butterfly (6 x 32-bit shuffles)
    float wv = bv;
    #pragma unroll
    for (int mask = 1; mask < 64; mask <<= 1)
      wv = fmaxf(wv, __shfl_xor(wv, mask));
    // lowest tied lane holds the smallest candidate index
    unsigned long long tied = __ballot(bv == wv);
    int wl = __ffsll(tied) - 1;
    int wi = __shfl(bi, wl);
    unsigned long long key =
        ((unsigned long long)__float_as_uint(wv) << 32) | (unsigned int)(~wi);
    const int buf = s & 1;
    if ((tid & 63) == 0) partial[buf][tid >> 6] = key;
    __syncthreads();
    // all threads reduce the 8 wave partials redundantly
    unsigned long long k0 = partial[buf][0];
    #pragma unroll
    for (int w = 1; w < 8; ++w) {
      unsigned long long o = partial[buf][w];
      k0 = (o > k0) ? o : k0;
    }
    const int widx = (int)(~(unsigned int)(k0 & 0xFFFFFFFFull));
    const float4 c = sp4[widx];
    cx = c.x; cy = c.y; cz = c.z;
    if (tid == 0) swidx[s] = (unsigned short)widx;
  }
  __syncthreads();
  // bulk write-out of the selected centroids
  for (int s = tid; s < M; s += FPS_T) {
    const float4 c = sp4[swidx[s]];
    q4[b * M + s] = c;
    out_q[b * 3 * M + s]         = c.x;
    out_q[b * 3 * M + M + s]     = c.y;
    out_q[b * 3 * M + 2 * M + s] = c.z;
  }
}

// ---------------------------------------------------------------- ball query
// One wave per centroid: first K in-radius indices ascending; pad with first.
__global__ __launch_bounds__(256) void ballquery_kernel(
    const float4* __restrict__ pts4, const float4* __restrict__ q4, int* __restrict__ nbr)
{
  __shared__ int slot[4][K];
  const int wv = threadIdx.x >> 6, lane = threadIdx.x & 63;
  const int qid = blockIdx.x * 4 + wv;
  const int b = qid >> 11;
  const float4 qc = q4[qid];
  const float4* pb = pts4 + (size_t)b * N;
  const float r2 = 0.04f;                 // float(0.2**2), strict <
  int count = 0;
  for (int c0 = 0; c0 < N; c0 += 64) {
    float4 p = pb[c0 + lane];
    float dx = __fsub_rn(p.x, qc.x), dy = __fsub_rn(p.y, qc.y), dz = __fsub_rn(p.z, qc.z);
    float d2 = __fadd_rn(__fadd_rn(__fmul_rn(dx, dx), __fmul_rn(dy, dy)), __fmul_rn(dz, dz));
    bool in = d2 < r2;
    unsigned long long mask = __ballot(in);
    int pos = count + (int)__popcll(mask & ((1ull << lane) - 1ull));
    if (in && pos < K) slot[wv][pos] = c0 + lane;
    count += (int)__popcll(mask);
    if (count >= K) break;
  }
  __syncthreads();
  int valid = count < K ? count : K;
  int v = 0;
  if (valid > 0) {
    int first = slot[wv][0];
    v = (lane < valid) ? slot[wv][lane] : first;
  }
  nbr[(size_t)qid * K + lane] = v;
}

// ---------------------------------------------------------------- MLP chain
// One wave per (b,m): 64 rows. Thread tile 8 rows x 8 channels.
// x tile in LDS [k][row]; weights (pre-transposed k-major) from global/L2.
DEVFN void conv_tile(float acc[8][8], const float (&xt)[C0 + 1][64],
                     const float* __restrict__ wT, int KK, int OC, int choff, int rg)
{
  #pragma unroll
  for (int i = 0; i < 8; ++i)
    #pragma unroll
    for (int j = 0; j < 8; ++j) acc[i][j] = 0.f;
  for (int k = 0; k < KK; ++k) {
    const float4 xa = *(const float4*)&xt[k][rg * 8];
    const float4 xb = *(const float4*)&xt[k][rg * 8 + 4];
    const float4 wa = *(const float4*)(wT + (size_t)k * OC + choff);
    const float4 wb = *(const float4*)(wT + (size_t)k * OC + choff + 4);
    const float xs[8] = {xa.x, xa.y, xa.z, xa.w, xb.x, xb.y, xb.z, xb.w};
    const float wv[8] = {wa.x, wa.y, wa.z, wa.w, wb.x, wb.y, wb.z, wb.w};
    #pragma unroll
    for (int i = 0; i < 8; ++i)
      #pragma unroll
      for (int j = 0; j < 8; ++j) acc[i][j] = fmaf(xs[i], wv[j], acc[i][j]);
  }
}

DEVFN void bn_relu_store(const float acc[8][8], const float* __restrict__ sc,
                         const float* __restrict__ sh, int choff, int rg,
                         float (&xt)[C0 + 1][64])
{
  float4 s0 = *(const float4*)(sc + choff), s1 = *(const float4*)(sc + choff + 4);
  float4 h0 = *(const float4*)(sh + choff), h1 = *(const float4*)(sh + choff + 4);
  const float scv[8] = {s0.x, s0.y, s0.z, s0.w, s1.x, s1.y, s1.z, s1.w};
  const float shv[8] = {h0.x, h0.y, h0.z, h0.w, h1.x, h1.y, h1.z, h1.w};
  __syncthreads();   // all lanes done reading xt
  #pragma unroll
  for (int j = 0; j < 8; ++j) {
    float4 a, b;
    a.x = fmaxf(fmaf(acc[0][j], scv[j], shv[j]), 0.f);
    a.y = fmaxf(fmaf(acc[1][j], scv[j], shv[j]), 0.f);
    a.z = fmaxf(fmaf(acc[2][j], scv[j], shv[j]), 0.f);
    a.w = fmaxf(fmaf(acc[3][j], scv[j], shv[j]), 0.f);
    b.x = fmaxf(fmaf(acc[4][j], scv[j], shv[j]), 0.f);
    b.y = fmaxf(fmaf(acc[5][j], scv[j], shv[j]), 0.f);
    b.z = fmaxf(fmaf(acc[6][j], scv[j], shv[j]), 0.f);
    b.w = fmaxf(fmaf(acc[7][j], scv[j], shv[j]), 0.f);
    *(float4*)&xt[choff + j][rg * 8]     = a;
    *(float4*)&xt[choff + j][rg * 8 + 4] = b;
  }
  __syncthreads();   // writes visible before next conv
}

DEVFN void stats_tile(const float acc[8][8], int chbase, int lane, int qid,
                      float* __restrict__ Psum, float* __restrict__ Psq)
{
  #pragma unroll
  for (int j = 0; j < 8; ++j) {
    float s = 0.f, q = 0.f;
    #pragma unroll
    for (int i = 0; i < 8; ++i) { s += acc[i][j]; q = fmaf(acc[i][j], acc[i][j], q); }
    s += __shfl_xor(s, 8);  q += __shfl_xor(q, 8);
    s += __shfl_xor(s, 16); q += __shfl_xor(q, 16);
    s += __shfl_xor(s, 32); q += __shfl_xor(q, 32);
    if ((lane >> 3) == 0) {
      Psum[(size_t)(chbase + j) * NB_CHAIN + qid] = s;
      Psq [(size_t)(chbase + j) * NB_CHAIN + qid] = q;
    }
  }
}

// per-(qid,ch) max AND min of pre-BN conv3 output over the K=64 rows.
// maxpool commutes with monotone BN+ReLU: out = relu(sc*max+sh) if sc>=0
// else relu(sc*min+sh) -- bit-exact (fma monotone in its multiplicand).
DEVFN void maxmin_tile(const float acc[8][8], int chbase, int lane, int qid,
                       float* __restrict__ ymax, float* __restrict__ ymin)
{
  #pragma unroll
  for (int j = 0; j < 8; ++j) {
    float mx = acc[0][j], mn = acc[0][j];
    #pragma unroll
    for (int i = 1; i < 8; ++i) { mx = fmaxf(mx, acc[i][j]); mn = fminf(mn, acc[i][j]); }
    mx = fmaxf(mx, __shfl_xor(mx, 8));  mn = fminf(mn, __shfl_xor(mn, 8));
    mx = fmaxf(mx, __shfl_xor(mx, 16)); mn = fminf(mn, __shfl_xor(mn, 16));
    mx = fmaxf(mx, __shfl_xor(mx, 32)); mn = fminf(mn, __shfl_xor(mn, 32));
    if ((lane >> 3) == 0) {
      ymax[(size_t)(chbase + j) * NB_CHAIN + qid] = mx;
      ymin[(size_t)(chbase + j) * NB_CHAIN + qid] = mn;
    }
  }
}

template <int PHASE>
__global__ __launch_bounds__(64) void chain_kernel(
    const float4* __restrict__ pts4, const float* __restrict__ ft,
    const float4* __restrict__ q4, const int* __restrict__ nbr,
    const float* __restrict__ w0T, const float* __restrict__ w1T, const float* __restrict__ w2T,
    const float* __restrict__ sc1, const float* __restrict__ sh1,
    const float* __restrict__ sc2, const float* __restrict__ sh2,
    float* __restrict__ Psum, float* __restrict__ Psq,
    float* __restrict__ ymax, float* __restrict__ ymin)
{
  __shared__ float xt[C0 + 1][64];            // [k][row], 17.4 KB
  const int qid = blockIdx.x;
  const int b = qid >> 11;
  const int lane = threadIdx.x;
  const int rg = lane >> 3, cg = lane & 7;

  // stage x0 = [rel(3), feats(64)] transposed into LDS
  const int i = nbr[(size_t)qid * K + lane];
  const float4 qc = q4[qid];
  const float4 p = pts4[(size_t)b * N + i];
  xt[0][lane] = p.x - qc.x;
  xt[1][lane] = p.y - qc.y;
  xt[2][lane] = p.z - qc.z;
  const float4* fr = (const float4*)(ft + (size_t)(b * N + i) * 64);
  #pragma unroll
  for (int c = 0; c < 16; ++c) {
    float4 f = fr[c];
    xt[3 + 4 * c + 0][lane] = f.x;
    xt[3 + 4 * c + 1][lane] = f.y;
    xt[3 + 4 * c + 2][lane] = f.z;
    xt[3 + 4 * c + 3][lane] = f.w;
  }
  __syncthreads();

  float acc[8][8];
  conv_tile(acc, xt, w0T, 67, 64, cg * 8, rg);              // conv1
  if (PHASE == 1) { stats_tile(acc, cg * 8, lane, qid, Psum, Psq); return; }

  bn_relu_store(acc, sc1, sh1, cg * 8, rg, xt);             // h1 -> LDS
  conv_tile(acc, xt, w1T, 64, 64, cg * 8, rg);              // conv2
  if (PHASE == 2) { stats_tile(acc, cg * 8, lane, qid, Psum, Psq); return; }

  bn_relu_store(acc, sc2, sh2, cg * 8, rg, xt);             // h2 -> LDS
  conv_tile(acc, xt, w2T, 64, 128, cg * 8, rg);             // conv3 half 0
  stats_tile(acc, cg * 8, lane, qid, Psum, Psq);
  maxmin_tile(acc, cg * 8, lane, qid, ymax, ymin);
  conv_tile(acc, xt, w2T, 64, 128, 64 + cg * 8, rg);        // conv3 half 1
  stats_tile(acc, 64 + cg * 8, lane, qid, Psum, Psq);
  maxmin_tile(acc, 64 + cg * 8, lane, qid, ymax, ymin);
}

// ---------------------------------------------------------------- stats reduce
__global__ __launch_bounds__(256) void reduce_stats(
    const float* __restrict__ Psum, const float* __restrict__ Psq,
    const float* __restrict__ g, const float* __restrict__ beta,
    float* __restrict__ scale, float* __restrict__ shift)
{
  __shared__ float ls[256], lq[256];
  const int o = blockIdx.x, t = threadIdx.x;
  float s = 0.f, q = 0.f;
  for (int x = t; x < NB_CHAIN; x += 256) {
    s += Psum[(size_t)o * NB_CHAIN + x];
    q += Psq [(size_t)o * NB_CHAIN + x];
  }
  ls[t] = s; lq[t] = q;
  __syncthreads();
  for (int st = 128; st > 0; st >>= 1) {
    if (t < st) { ls[t] += ls[t + st]; lq[t] += lq[t + st]; }
    __syncthreads();
  }
  if (t == 0) {
    const float inv = 1.f / (float)NROW;
    float mu = ls[0] * inv;
    float var = lq[0] * inv - mu * mu;
    float scv = g[o] / sqrtf(var + 1e-5f);
    scale[o] = scv;
    shift[o] = beta[o] - mu * scv;
  }
}

// ---------------------------------------------------------------- final BN+maxpool
// out[(b*128+ch)*M + m] = relu(sc*ymax+sh)  (sc>=0)  else relu(sc*ymin+sh)
__global__ __launch_bounds__(256) void bn_final(
    const float* __restrict__ ymax, const float* __restrict__ ymin,
    const float* __restrict__ sc3, const float* __restrict__ sh3,
    float* __restrict__ out1)
{
  const int idx = blockIdx.x * 256 + threadIdx.x;    // (b*128+ch)*2048 + m
  const int ch = (idx >> 11) & 127;
  const int qid = ((idx >> 18) << 11) | (idx & 2047);
  const float sc = sc3[ch], sh = sh3[ch];
  const float v = (sc >= 0.f) ? ymax[(size_t)ch * NB_CHAIN + qid]
                              : ymin[(size_t)ch * NB_CHAIN + qid];
  out1[idx] = fmaxf(fmaf(v, sc, sh), 0.f);
}

// ---------------------------------------------------------------- launcher
extern "C" void kernel_launch(void* const* d_in, const int* in_sizes, int n_in,
                              void* d_out, int out_size, void* d_ws, size_t ws_size,
                              hipStream_t stream)
{
  const float* P  = (const float*)d_in[0];
  const float* F  = (const float*)d_in[1];
  const float* W0 = (const float*)d_in[2];
  const float* g0 = (const float*)d_in[3];
  const float* b0 = (const float*)d_in[4];
  const float* W1 = (const float*)d_in[5];
  const float* g1 = (const float*)d_in[6];
  const float* b1 = (const float*)d_in[7];
  const float* W2 = (const float*)d_in[8];
  const float* g2 = (const float*)d_in[9];
  const float* b2 = (const float*)d_in[10];

  float* out_q = (float*)d_out;           // (B,3,M)
  float* out_f = out_q + B * 3 * M;       // (B,128,M)

  char* w = (char*)d_ws;
  size_t off = 0;
  auto alloc = [&](size_t bytes) -> void* {
    off = (off + 255) & ~(size_t)255;
    void* p = w + off;
    off += bytes;
    return p;
  };
  float4* pts4 = (float4*)alloc((size_t)B * N * sizeof(float4));
  float*  ft   = (float*) alloc((size_t)B * N * 64 * 4);
  float*  w0T  = (float*) alloc(68 * 64 * 4);
  float*  w1T  = (float*) alloc(64 * 64 * 4);
  float*  w2T  = (float*) alloc(64 * 128 * 4);
  float4* q4   = (float4*)alloc((size_t)B * M * sizeof(float4));
  int*    nbr  = (int*)   alloc((size_t)B * M * K * 4);
  float*  Psum = (float*) alloc((size_t)128 * NB_CHAIN * 4);
  float*  Psq  = (float*) alloc((size_t)128 * NB_CHAIN * 4);
  float*  ymax = (float*) alloc((size_t)128 * NB_CHAIN * 4);
  float*  ymin = (float*) alloc((size_t)128 * NB_CHAIN * 4);
  float*  bnp  = (float*) alloc(6 * 128 * 4);
  float *sc1 = bnp, *sh1 = bnp + 128, *sc2 = bnp + 256, *sh2 = bnp + 384,
        *sc3 = bnp + 512, *sh3 = bnp + 640;
  (void)ws_size; (void)in_sizes; (void)n_in; (void)out_size;

  transpose_kernel<<<B * N / 256, 256, 0, stream>>>(P, F, pts4, ft);
  prep_weights<<<1, 256, 0, stream>>>(W0, W1, W2, w0T, w1T, w2T);
  fps_kernel<<<B, FPS_T, 0, stream>>>(P, q4, out_q);
  ballquery_kernel<<<B * M / 4, 256, 0, stream>>>(pts4, q4, nbr);

  chain_kernel<1><<<NB_CHAIN, 64, 0, stream>>>(pts4, ft, q4, nbr, w0T, w1T, w2T,
      sc1, sh1, sc2, sh2, Psum, Psq, ymax, ymin);
  reduce_stats<<<64, 256, 0, stream>>>(Psum, Psq, g0, b0, sc1, sh1);
  chain_kernel<2><<<NB_CHAIN, 64, 0, stream>>>(pts4, ft, q4, nbr, w0T, w1T, w2T,
      sc1, sh1, sc2, sh2, Psum, Psq, ymax, ymin);
  reduce_stats<<<64, 256, 0, stream>>>(Psum, Psq, g1, b1, sc2, sh2);
  chain_kernel<3><<<NB_CHAIN, 64, 0, stream>>>(pts4, ft, q4, nbr, w0T, w1T, w2T,
      sc1, sh1, sc2, sh2, Psum, Psq, ymax, ymin);
  reduce_stats<<<128, 256, 0, stream>>>(Psum, Psq, g2, b2, sc3, sh3);
  bn_final<<<NB_CHAIN * 128 / 256, 256, 0, stream>>>(ymax, ymin, sc3, sh3, out_f);
}

// Round 7
// 2346.276 us; speedup vs baseline: 1.3899x; 1.2304x over previous
//
#include <hip/hip_runtime.h>
#include <math.h>

// PointNet++ SetAbstraction for MI355X.
// B=4 N=8192 M=2048 K=64 C_IN=64, dims 67->64->64->128, radius 0.2.
// Exactness-critical paths (FPS argmax, ball-query radius test) use
// __f*_rn intrinsics to bit-match plain IEEE mul/add (no FMA contraction).

constexpr int B = 4, N = 8192, M = 2048, K = 64;
constexpr int C0 = 67;              // 3 + 64 input channels
constexpr int NB_CHAIN = B * M;     // one block per (b,m) = 8192
constexpr int NROW = B * M * K;     // 524288 rows through the MLP

#define DEVFN static __device__ __forceinline__

// DPP-shifted copy: invalid lanes get 0 (safe under max of values >= 0).
template <int CTRL>
DEVFN float dpp_shift0(float x) {
  return __uint_as_float((unsigned)__builtin_amdgcn_update_dpp(
      0, (int)__float_as_uint(x), CTRL, 0xf, 0xf, true));
}

// ---------------------------------------------------------------- transpose
__global__ __launch_bounds__(256) void transpose_kernel(
    const float* __restrict__ P, const float* __restrict__ F,
    float4* __restrict__ pts4, float* __restrict__ ft)
{
  int g = blockIdx.x * 256 + threadIdx.x;        // 0 .. B*N-1
  int b = g >> 13, i = g & (N - 1);
  const float* Pb = P + (size_t)b * 3 * N;
  pts4[g] = make_float4(Pb[i], Pb[N + i], Pb[2 * N + i], 0.f);
  const float* Fb = F + (size_t)b * 64 * N;
  float* o = ft + (size_t)g * 64;
  #pragma unroll 8
  for (int c = 0; c < 64; ++c) o[c] = Fb[(size_t)c * N + i];
}

__global__ __launch_bounds__(256) void prep_weights(
    const float* __restrict__ W0, const float* __restrict__ W1,
    const float* __restrict__ W2,
    float* __restrict__ w0T, float* __restrict__ w1T, float* __restrict__ w2T)
{
  int t = threadIdx.x;
  for (int x = t; x < 67 * 64; x += 256) { int k = x >> 6, o = x & 63;  w0T[x] = W0[o * 67 + k]; }
  for (int x = t; x < 64 * 64; x += 256) { int k = x >> 6, o = x & 63;  w1T[x] = W1[o * 64 + k]; }
  for (int x = t; x < 64 * 128; x += 256){ int k = x >> 7, o = x & 127; w2T[x] = W2[o * 64 + k]; }
}

// ---------------------------------------------------------------- FPS
// One block per batch; 512 threads (2 waves/SIMD). Thread t owns
// CONTIGUOUS points [16t,16t+16) -> lane order == index order, so
// value-tie -> lowest lane wins. Wave argmax: DPP max chain
// (row_shr 1/2/4/8 + row_bcast 15/31, pure-VALU, no LDS round-trips)
// -> lane 63 has wave max -> readlane + ballot for owner lane.
// Cross-wave: u64 key (value_bits<<32 | ~idx). No global ops in loop.
constexpr int FPS_T = 512;
constexpr int FPS_PT = N / FPS_T;   // 16

__global__ __launch_bounds__(512) void fps_kernel(
    const float* __restrict__ P, float4* __restrict__ q4, float* __restrict__ out_q)
{
  __shared__ float4 sp4[N];                             // 128 KB point table
  __shared__ __align__(16) unsigned long long partial[2][8];
  __shared__ unsigned short swidx[M];                   // 4 KB winner idx
  const int b = blockIdx.x, tid = threadIdx.x;
  const float* Pb = P + (size_t)b * 3 * N;

  float px[FPS_PT], py[FPS_PT], pz[FPS_PT], mind[FPS_PT];
  #pragma unroll
  for (int j = 0; j < FPS_PT; ++j) {
    int i = tid * FPS_PT + j;                           // contiguous block
    px[j] = Pb[i]; py[j] = Pb[N + i]; pz[j] = Pb[2 * N + i];
    sp4[i] = make_float4(px[j], py[j], pz[j], 0.f);
    mind[j] = 1e10f;
  }
  if (tid == 0) swidx[0] = 0;                           // centroid 0 = point 0
  __syncthreads();

  float cx = Pb[0], cy = Pb[N], cz = Pb[2 * N];

  for (int s = 1; s < M; ++s) {
    // phase A: exact min-update + per-thread argmax (value, lowest idx)
    float bv = -1.f; int bi = 0;
    #pragma unroll
    for (int j = 0; j < FPS_PT; ++j) {
      float dx = __fsub_rn(px[j], cx), dy = __fsub_rn(py[j], cy), dz = __fsub_rn(pz[j], cz);
      float d  = __fadd_rn(__fadd_rn(__fmul_rn(dx, dx), __fmul_rn(dy, dy)), __fmul_rn(dz, dz));
      float mm = fminf(mind[j], d);
      mind[j] = mm;
      bool tk = mm > bv;                 // strict > keeps lowest index (j ascending)
      bv = tk ? mm : bv;
      bi = tk ? tid * FPS_PT + j : bi;
    }
    // wave argmax via DPP (all values >= 0; 0-fill is neutral for max)
    float r = bv;
    r = fmaxf(r, dpp_shift0<0x111>(r));   // row_shr:1
    r = fmaxf(r, dpp_shift0<0x112>(r));   // row_shr:2
    r = fmaxf(r, dpp_shift0<0x114>(r));   // row_shr:4
    r = fmaxf(r, dpp_shift0<0x118>(r));   // row_shr:8  -> lane15 of each row
    r = fmaxf(r, dpp_shift0<0x142>(r));   // row_bcast:15
    r = fmaxf(r, dpp_shift0<0x143>(r));   // row_bcast:31 -> lane 63 global
    float wv = __shfl(r, 63);
    unsigned long long tied = __ballot(bv == wv);
    int wl = __ffsll(tied) - 1;
    int wi = __shfl(bi, wl);
    unsigned long long key =
        ((unsigned long long)__float_as_uint(wv) << 32) | (unsigned int)(~wi);
    const int buf = s & 1;
    if ((tid & 63) == 0) partial[buf][tid >> 6] = key;
    __syncthreads();
    // all threads reduce the 8 wave partials redundantly
    unsigned long long k0 = partial[buf][0];
    #pragma unroll
    for (int w = 1; w < 8; ++w) {
      unsigned long long o = partial[buf][w];
      k0 = (o > k0) ? o : k0;
    }
    const int widx = (int)(~(unsigned int)(k0 & 0xFFFFFFFFull));
    const float4 c = sp4[widx];
    cx = c.x; cy = c.y; cz = c.z;
    if (tid == 0) swidx[s] = (unsigned short)widx;
  }
  __syncthreads();
  // bulk write-out of the selected centroids
  for (int s = tid; s < M; s += FPS_T) {
    const float4 c = sp4[swidx[s]];
    q4[b * M + s] = c;
    out_q[b * 3 * M + s]         = c.x;
    out_q[b * 3 * M + M + s]     = c.y;
    out_q[b * 3 * M + 2 * M + s] = c.z;
  }
}

// ---------------------------------------------------------------- ball query
// One wave per centroid: first K in-radius indices ascending; pad with first.
__global__ __launch_bounds__(256) void ballquery_kernel(
    const float4* __restrict__ pts4, const float4* __restrict__ q4, int* __restrict__ nbr)
{
  __shared__ int slot[4][K];
  const int wv = threadIdx.x >> 6, lane = threadIdx.x & 63;
  const int qid = blockIdx.x * 4 + wv;
  const int b = qid >> 11;
  const float4 qc = q4[qid];
  const float4* pb = pts4 + (size_t)b * N;
  const float r2 = 0.04f;                 // float(0.2**2), strict <
  int count = 0;
  for (int c0 = 0; c0 < N; c0 += 64) {
    float4 p = pb[c0 + lane];
    float dx = __fsub_rn(p.x, qc.x), dy = __fsub_rn(p.y, qc.y), dz = __fsub_rn(p.z, qc.z);
    float d2 = __fadd_rn(__fadd_rn(__fmul_rn(dx, dx), __fmul_rn(dy, dy)), __fmul_rn(dz, dz));
    bool in = d2 < r2;
    unsigned long long mask = __ballot(in);
    int pos = count + (int)__popcll(mask & ((1ull << lane) - 1ull));
    if (in && pos < K) slot[wv][pos] = c0 + lane;
    count += (int)__popcll(mask);
    if (count >= K) break;
  }
  __syncthreads();
  int valid = count < K ? count : K;
  int v = 0;
  if (valid > 0) {
    int first = slot[wv][0];
    v = (lane < valid) ? slot[wv][lane] : first;
  }
  nbr[(size_t)qid * K + lane] = v;
}

// ---------------------------------------------------------------- MLP chain
// One wave per (b,m): 64 rows. Thread tile 8 rows x 8 channels.
// x tile in LDS [k][row]; weights (pre-transposed k-major) from global/L2.
DEVFN void conv_tile(float acc[8][8], const float (&xt)[C0 + 1][64],
                     const float* __restrict__ wT, int KK, int OC, int choff, int rg)
{
  #pragma unroll
  for (int i = 0; i < 8; ++i)
    #pragma unroll
    for (int j = 0; j < 8; ++j) acc[i][j] = 0.f;
  for (int k = 0; k < KK; ++k) {
    const float4 xa = *(const float4*)&xt[k][rg * 8];
    const float4 xb = *(const float4*)&xt[k][rg * 8 + 4];
    const float4 wa = *(const float4*)(wT + (size_t)k * OC + choff);
    const float4 wb = *(const float4*)(wT + (size_t)k * OC + choff + 4);
    const float xs[8] = {xa.x, xa.y, xa.z, xa.w, xb.x, xb.y, xb.z, xb.w};
    const float wv[8] = {wa.x, wa.y, wa.z, wa.w, wb.x, wb.y, wb.z, wb.w};
    #pragma unroll
    for (int i = 0; i < 8; ++i)
      #pragma unroll
      for (int j = 0; j < 8; ++j) acc[i][j] = fmaf(xs[i], wv[j], acc[i][j]);
  }
}

DEVFN void bn_relu_store(const float acc[8][8], const float* __restrict__ sc,
                         const float* __restrict__ sh, int choff, int rg,
                         float (&xt)[C0 + 1][64])
{
  float4 s0 = *(const float4*)(sc + choff), s1 = *(const float4*)(sc + choff + 4);
  float4 h0 = *(const float4*)(sh + choff), h1 = *(const float4*)(sh + choff + 4);
  const float scv[8] = {s0.x, s0.y, s0.z, s0.w, s1.x, s1.y, s1.z, s1.w};
  const float shv[8] = {h0.x, h0.y, h0.z, h0.w, h1.x, h1.y, h1.z, h1.w};
  __syncthreads();   // all lanes done reading xt
  #pragma unroll
  for (int j = 0; j < 8; ++j) {
    float4 a, b;
    a.x = fmaxf(fmaf(acc[0][j], scv[j], shv[j]), 0.f);
    a.y = fmaxf(fmaf(acc[1][j], scv[j], shv[j]), 0.f);
    a.z = fmaxf(fmaf(acc[2][j], scv[j], shv[j]), 0.f);
    a.w = fmaxf(fmaf(acc[3][j], scv[j], shv[j]), 0.f);
    b.x = fmaxf(fmaf(acc[4][j], scv[j], shv[j]), 0.f);
    b.y = fmaxf(fmaf(acc[5][j], scv[j], shv[j]), 0.f);
    b.z = fmaxf(fmaf(acc[6][j], scv[j], shv[j]), 0.f);
    b.w = fmaxf(fmaf(acc[7][j], scv[j], shv[j]), 0.f);
    *(float4*)&xt[choff + j][rg * 8]     = a;
    *(float4*)&xt[choff + j][rg * 8 + 4] = b;
  }
  __syncthreads();   // writes visible before next conv
}

DEVFN void stats_tile(const float acc[8][8], int chbase, int lane, int qid,
                      float* __restrict__ Psum, float* __restrict__ Psq)
{
  #pragma unroll
  for (int j = 0; j < 8; ++j) {
    float s = 0.f, q = 0.f;
    #pragma unroll
    for (int i = 0; i < 8; ++i) { s += acc[i][j]; q = fmaf(acc[i][j], acc[i][j], q); }
    s += __shfl_xor(s, 8);  q += __shfl_xor(q, 8);
    s += __shfl_xor(s, 16); q += __shfl_xor(q, 16);
    s += __shfl_xor(s, 32); q += __shfl_xor(q, 32);
    if ((lane >> 3) == 0) {
      Psum[(size_t)(chbase + j) * NB_CHAIN + qid] = s;
      Psq [(size_t)(chbase + j) * NB_CHAIN + qid] = q;
    }
  }
}

// per-(qid,ch) max AND min of pre-BN conv3 output over the K=64 rows.
// maxpool commutes with monotone BN+ReLU: out = relu(sc*max+sh) if sc>=0
// else relu(sc*min+sh) -- bit-exact (fma monotone in its multiplicand).
DEVFN void maxmin_tile(const float acc[8][8], int chbase, int lane, int qid,
                       float* __restrict__ ymax, float* __restrict__ ymin)
{
  #pragma unroll
  for (int j = 0; j < 8; ++j) {
    float mx = acc[0][j], mn = acc[0][j];
    #pragma unroll
    for (int i = 1; i < 8; ++i) { mx = fmaxf(mx, acc[i][j]); mn = fminf(mn, acc[i][j]); }
    mx = fmaxf(mx, __shfl_xor(mx, 8));  mn = fminf(mn, __shfl_xor(mn, 8));
    mx = fmaxf(mx, __shfl_xor(mx, 16)); mn = fminf(mn, __shfl_xor(mn, 16));
    mx = fmaxf(mx, __shfl_xor(mx, 32)); mn = fminf(mn, __shfl_xor(mn, 32));
    if ((lane >> 3) == 0) {
      ymax[(size_t)(chbase + j) * NB_CHAIN + qid] = mx;
      ymin[(size_t)(chbase + j) * NB_CHAIN + qid] = mn;
    }
  }
}

// gather input tile -> LDS (shared by P1 variants)
DEVFN void gather_x0(const float4* __restrict__ pts4, const float* __restrict__ ft,
                     const float4* __restrict__ q4, const int* __restrict__ nbr,
                     int qid, int b, int lane, float (&xt)[C0 + 1][64])
{
  const int i = nbr[(size_t)qid * K + lane];
  const float4 qc = q4[qid];
  const float4 p = pts4[(size_t)b * N + i];
  xt[0][lane] = p.x - qc.x;
  xt[1][lane] = p.y - qc.y;
  xt[2][lane] = p.z - qc.z;
  const float4* fr = (const float4*)(ft + (size_t)(b * N + i) * 64);
  #pragma unroll
  for (int c = 0; c < 16; ++c) {
    float4 f = fr[c];
    xt[3 + 4 * c + 0][lane] = f.x;
    xt[3 + 4 * c + 1][lane] = f.y;
    xt[3 + 4 * c + 2][lane] = f.z;
    xt[3 + 4 * c + 3][lane] = f.w;
  }
  __syncthreads();
}

// acc <-> y buffer (layout y[qid*4096 + ch*64 + k], f32, exact)
DEVFN void y_store(const float acc[8][8], float* __restrict__ y, int qid, int rg, int cg)
{
  float* base = y + (size_t)qid * 4096 + (size_t)(cg * 8) * 64 + rg * 8;
  #pragma unroll
  for (int j = 0; j < 8; ++j) {
    float4 a = make_float4(acc[0][j], acc[1][j], acc[2][j], acc[3][j]);
    float4 c = make_float4(acc[4][j], acc[5][j], acc[6][j], acc[7][j]);
    *(float4*)(base + (size_t)j * 64)     = a;
    *(float4*)(base + (size_t)j * 64 + 4) = c;
  }
}
DEVFN void y_load(float acc[8][8], const float* __restrict__ y, int qid, int rg, int cg)
{
  const float* base = y + (size_t)qid * 4096 + (size_t)(cg * 8) * 64 + rg * 8;
  #pragma unroll
  for (int j = 0; j < 8; ++j) {
    float4 a = *(const float4*)(base + (size_t)j * 64);
    float4 c = *(const float4*)(base + (size_t)j * 64 + 4);
    acc[0][j] = a.x; acc[1][j] = a.y; acc[2][j] = a.z; acc[3][j] = a.w;
    acc[4][j] = c.x; acc[5][j] = c.y; acc[6][j] = c.z; acc[7][j] = c.w;
  }
}

// --- materialized pipeline (single compute of each conv) ---
__global__ __launch_bounds__(64) void chain_p1(
    const float4* __restrict__ pts4, const float* __restrict__ ft,
    const float4* __restrict__ q4, const int* __restrict__ nbr,
    const float* __restrict__ w0T,
    float* __restrict__ Psum, float* __restrict__ Psq, float* __restrict__ y)
{
  __shared__ float xt[C0 + 1][64];
  const int qid = blockIdx.x, b = qid >> 11, lane = threadIdx.x;
  const int rg = lane >> 3, cg = lane & 7;
  gather_x0(pts4, ft, q4, nbr, qid, b, lane, xt);
  float acc[8][8];
  conv_tile(acc, xt, w0T, 67, 64, cg * 8, rg);
  stats_tile(acc, cg * 8, lane, qid, Psum, Psq);
  y_store(acc, y, qid, rg, cg);
}

template <int LAYER>   // 2: conv2 (store y2); 3: conv3 (stats+maxmin)
__global__ __launch_bounds__(64) void chain_p23(
    const float* __restrict__ wT, const float* __restrict__ sc,
    const float* __restrict__ sh,
    float* __restrict__ Psum, float* __restrict__ Psq,
    float* __restrict__ y, float* __restrict__ ymax, float* __restrict__ ymin)
{
  __shared__ float xt[C0 + 1][64];
  const int qid = blockIdx.x, lane = threadIdx.x;
  const int rg = lane >> 3, cg = lane & 7;
  float acc[8][8];
  y_load(acc, y, qid, rg, cg);                       // previous pre-BN y
  bn_relu_store(acc, sc, sh, cg * 8, rg, xt);        // h -> LDS
  if (LAYER == 2) {
    conv_tile(acc, xt, wT, 64, 64, cg * 8, rg);
    stats_tile(acc, cg * 8, lane, qid, Psum, Psq);
    y_store(acc, y, qid, rg, cg);
  } else {
    conv_tile(acc, xt, wT, 64, 128, cg * 8, rg);     // conv3 half 0
    stats_tile(acc, cg * 8, lane, qid, Psum, Psq);
    maxmin_tile(acc, cg * 8, lane, qid, ymax, ymin);
    conv_tile(acc, xt, wT, 64, 128, 64 + cg * 8, rg);// conv3 half 1
    stats_tile(acc, 64 + cg * 8, lane, qid, Psum, Psq);
    maxmin_tile(acc, 64 + cg * 8, lane, qid, ymax, ymin);
  }
}

// --- fallback recompute pipeline (used if ws too small for y buffer) ---
template <int PHASE>
__global__ __launch_bounds__(64) void chain_kernel(
    const float4* __restrict__ pts4, const float* __restrict__ ft,
    const float4* __restrict__ q4, const int* __restrict__ nbr,
    const float* __restrict__ w0T, const float* __restrict__ w1T, const float* __restrict__ w2T,
    const float* __restrict__ sc1, const float* __restrict__ sh1,
    const float* __restrict__ sc2, const float* __restrict__ sh2,
    float* __restrict__ Psum, float* __restrict__ Psq,
    float* __restrict__ ymax, float* __restrict__ ymin)
{
  __shared__ float xt[C0 + 1][64];
  const int qid = blockIdx.x, b = qid >> 11, lane = threadIdx.x;
  const int rg = lane >> 3, cg = lane & 7;
  gather_x0(pts4, ft, q4, nbr, qid, b, lane, xt);
  float acc[8][8];
  conv_tile(acc, xt, w0T, 67, 64, cg * 8, rg);
  if (PHASE == 1) { stats_tile(acc, cg * 8, lane, qid, Psum, Psq); return; }
  bn_relu_store(acc, sc1, sh1, cg * 8, rg, xt);
  conv_tile(acc, xt, w1T, 64, 64, cg * 8, rg);
  if (PHASE == 2) { stats_tile(acc, cg * 8, lane, qid, Psum, Psq); return; }
  bn_relu_store(acc, sc2, sh2, cg * 8, rg, xt);
  conv_tile(acc, xt, w2T, 64, 128, cg * 8, rg);
  stats_tile(acc, cg * 8, lane, qid, Psum, Psq);
  maxmin_tile(acc, cg * 8, lane, qid, ymax, ymin);
  conv_tile(acc, xt, w2T, 64, 128, 64 + cg * 8, rg);
  stats_tile(acc, 64 + cg * 8, lane, qid, Psum, Psq);
  maxmin_tile(acc, 64 + cg * 8, lane, qid, ymax, ymin);
}

// ---------------------------------------------------------------- stats reduce
__global__ __launch_bounds__(256) void reduce_stats(
    const float* __restrict__ Psum, const float* __restrict__ Psq,
    const float* __restrict__ g, const float* __restrict__ beta,
    float* __restrict__ scale, float* __restrict__ shift)
{
  __shared__ float ls[256], lq[256];
  const int o = blockIdx.x, t = threadIdx.x;
  float s = 0.f, q = 0.f;
  for (int x = t; x < NB_CHAIN; x += 256) {
    s += Psum[(size_t)o * NB_CHAIN + x];
    q += Psq [(size_t)o * NB_CHAIN + x];
  }
  ls[t] = s; lq[t] = q;
  __syncthreads();
  for (int st = 128; st > 0; st >>= 1) {
    if (t < st) { ls[t] += ls[t + st]; lq[t] += lq[t + st]; }
    __syncthreads();
  }
  if (t == 0) {
    const float inv = 1.f / (float)NROW;
    float mu = ls[0] * inv;
    float var = lq[0] * inv - mu * mu;
    float scv = g[o] / sqrtf(var + 1e-5f);
    scale[o] = scv;
    shift[o] = beta[o] - mu * scv;
  }
}

// ---------------------------------------------------------------- final BN+maxpool
__global__ __launch_bounds__(256) void bn_final(
    const float* __restrict__ ymax, const float* __restrict__ ymin,
    const float* __restrict__ sc3, const float* __restrict__ sh3,
    float* __restrict__ out1)
{
  const int idx = blockIdx.x * 256 + threadIdx.x;    // (b*128+ch)*2048 + m
  const int ch = (idx >> 11) & 127;
  const int qid = ((idx >> 18) << 11) | (idx & 2047);
  const float sc = sc3[ch], sh = sh3[ch];
  const float v = (sc >= 0.f) ? ymax[(size_t)ch * NB_CHAIN + qid]
                              : ymin[(size_t)ch * NB_CHAIN + qid];
  out1[idx] = fmaxf(fmaf(v, sc, sh), 0.f);
}

// ---------------------------------------------------------------- launcher
extern "C" void kernel_launch(void* const* d_in, const int* in_sizes, int n_in,
                              void* d_out, int out_size, void* d_ws, size_t ws_size,
                              hipStream_t stream)
{
  const float* P  = (const float*)d_in[0];
  const float* F  = (const float*)d_in[1];
  const float* W0 = (const float*)d_in[2];
  const float* g0 = (const float*)d_in[3];
  const float* b0 = (const float*)d_in[4];
  const float* W1 = (const float*)d_in[5];
  const float* g1 = (const float*)d_in[6];
  const float* b1 = (const float*)d_in[7];
  const float* W2 = (const float*)d_in[8];
  const float* g2 = (const float*)d_in[9];
  const float* b2 = (const float*)d_in[10];

  float* out_q = (float*)d_out;           // (B,3,M)
  float* out_f = out_q + B * 3 * M;       // (B,128,M)

  char* w = (char*)d_ws;
  size_t off = 0;
  auto alloc = [&](size_t bytes) -> void* {
    off = (off + 255) & ~(size_t)255;
    void* p = w + off;
    off += bytes;
    return p;
  };
  float4* pts4 = (float4*)alloc((size_t)B * N * sizeof(float4));
  float*  ft   = (float*) alloc((size_t)B * N * 64 * 4);
  float*  w0T  = (float*) alloc(68 * 64 * 4);
  float*  w1T  = (float*) alloc(64 * 64 * 4);
  float*  w2T  = (float*) alloc(64 * 128 * 4);
  float4* q4   = (float4*)alloc((size_t)B * M * sizeof(float4));
  int*    nbr  = (int*)   alloc((size_t)B * M * K * 4);
  float*  Psum = (float*) alloc((size_t)128 * NB_CHAIN * 4);
  float*  Psq  = (float*) alloc((size_t)128 * NB_CHAIN * 4);
  float*  ymax = (float*) alloc((size_t)128 * NB_CHAIN * 4);
  float*  ymin = (float*) alloc((size_t)128 * NB_CHAIN * 4);
  float*  bnp  = (float*) alloc(6 * 128 * 4);
  float *sc1 = bnp, *sh1 = bnp + 128, *sc2 = bnp + 256, *sh2 = bnp + 384,
        *sc3 = bnp + 512, *sh3 = bnp + 640;
  // y buffer: (B*M) x 64rows x 64ch f32 = 134.2 MB, reused for y1 then y2
  const size_t ybytes = (size_t)NB_CHAIN * 64 * 64 * 4;
  off = (off + 255) & ~(size_t)255;
  const bool have_y = (off + ybytes) <= ws_size;
  float* y = (float*)(w + off);
  (void)in_sizes; (void)n_in; (void)out_size;

  transpose_kernel<<<B * N / 256, 256, 0, stream>>>(P, F, pts4, ft);
  prep_weights<<<1, 256, 0, stream>>>(W0, W1, W2, w0T, w1T, w2T);
  fps_kernel<<<B, FPS_T, 0, stream>>>(P, q4, out_q);
  ballquery_kernel<<<B * M / 4, 256, 0, stream>>>(pts4, q4, nbr);

  if (have_y) {
    chain_p1<<<NB_CHAIN, 64, 0, stream>>>(pts4, ft, q4, nbr, w0T, Psum, Psq, y);
    reduce_stats<<<64, 256, 0, stream>>>(Psum, Psq, g0, b0, sc1, sh1);
    chain_p23<2><<<NB_CHAIN, 64, 0, stream>>>(w1T, sc1, sh1, Psum, Psq, y, ymax, ymin);
    reduce_stats<<<64, 256, 0, stream>>>(Psum, Psq, g1, b1, sc2, sh2);
    chain_p23<3><<<NB_CHAIN, 64, 0, stream>>>(w2T, sc2, sh2, Psum, Psq, y, ymax, ymin);
    reduce_stats<<<128, 256, 0, stream>>>(Psum, Psq, g2, b2, sc3, sh3);
  } else {
    chain_kernel<1><<<NB_CHAIN, 64, 0, stream>>>(pts4, ft, q4, nbr, w0T, w1T, w2T,
        sc1, sh1, sc2, sh2, Psum, Psq, ymax, ymin);
    reduce_stats<<<64, 256, 0, stream>>>(Psum, Psq, g0, b0, sc1, sh1);
    chain_kernel<2><<<NB_CHAIN, 64, 0, stream>>>(pts4, ft, q4, nbr, w0T, w1T, w2T,
        sc1, sh1, sc2, sh2, Psum, Psq, ymax, ymin);
    reduce_stats<<<64, 256, 0, stream>>>(Psum, Psq, g1, b1, sc2, sh2);
    chain_kernel<3><<<NB_CHAIN, 64, 0, stream>>>(pts4, ft, q4, nbr, w0T, w1T, w2T,
        sc1, sh1, sc2, sh2, Psum, Psq, ymax, ymin);
    reduce_stats<<<128, 256, 0, stream>>>(Psum, Psq, g2, b2, sc3, sh3);
  }
  bn_final<<<NB_CHAIN * 128 / 256, 256, 0, stream>>>(ymax, ymin, sc3, sh3, out_f);
}